// Round 19
// baseline (651.252 us; speedup 1.0000x reference)
//
#include <hip/hip_runtime.h>
#include <hip/hip_bf16.h>
#include <hip/hip_fp16.h>
#include <math.h>

#define BB 4
#define SS 2048
#define HIDDEN 2048
#define NHEADS 16
#define HDIM 128
#define BSROWS (BB * SS)
#define ATT_SCALE 0.08838834764831845f

typedef __attribute__((ext_vector_type(8))) _Float16 half8v;
typedef __attribute__((ext_vector_type(4))) float f32x4;
typedef __attribute__((ext_vector_type(16))) float f32x16;

static __device__ __forceinline__ unsigned encf(float x) {
  unsigned b = __float_as_uint(x);
  return (b & 0x80000000u) ? ~b : (b | 0x80000000u);
}
static __device__ __forceinline__ float decf(unsigned k) {
  unsigned b = (k & 0x80000000u) ? (k ^ 0x80000000u) : ~k;
  return __uint_as_float(b);
}
static __device__ __forceinline__ unsigned short f2h(float f) {
  _Float16 h = (_Float16)f;  // v_cvt_f16_f32, RNE
  return *(unsigned short*)&h;
}

// ---------------- small setup kernels ----------------

__global__ void rope_tables_k(float* __restrict__ ct, float* __restrict__ st) {
  int t = blockIdx.x;
  int d = threadIdx.x;  // 0..63
  float inv = powf(10000.0f, -(float)d * (1.0f / 64.0f));
  float a = (float)t * inv;
  ct[t * 64 + d] = cosf(a);
  st[t * 64 + d] = sinf(a);
}

__global__ void build_m_k(const float* __restrict__ kc, const float* __restrict__ kdw,
                          const float* __restrict__ vc, const float* __restrict__ vdw,
                          float* __restrict__ mk, float* __restrict__ mv) {
  int a = blockIdx.x;
  int c = threadIdx.x;
  const float* cw = blockIdx.y ? vc : kc;
  const float* dw = blockIdx.y ? vdw : kdw;
  float* m = blockIdx.y ? mv : mk;
  float acc = 0.f;
#pragma unroll
  for (int mm = 0; mm < 32; mm++) acc += cw[mm * 128 + a] * dw[c * 32 + mm];
  m[a * 128 + c] = acc;
}

__global__ void mm_init_k(unsigned* mmx) {
  int i = threadIdx.x;
  if (i < 4) mmx[i] = (i & 1) ? 0u : 0xFFFFFFFFu;
}

// fp32 -> fp16
__global__ void split_fp16_k(const float* __restrict__ src,
                             unsigned short* __restrict__ hi, int n4) {
  int i = blockIdx.x * 256 + threadIdx.x;
  int stride = gridDim.x * 256;
  for (; i < n4; i += stride) {
    float4 v = ((const float4*)src)[i];
    ((ushort4*)hi)[i] = make_ushort4(f2h(v.x), f2h(v.y), f2h(v.z), f2h(v.w));
  }
}

// ---------------- 256x256 deep-pipelined fp16 MFMA GEMM ----------------
// (r15-proven) All 4 half-tiles of t+1 staged at top of ph1(t); vmcnt(8)
// before ph2, vmcnt(2) at tile end. Output fp32 Cf or fp16 Ch.
__global__ __launch_bounds__(512, 2) void gemm_f16_ph_k(
    const unsigned short* __restrict__ A, const unsigned short* __restrict__ B,
    float* __restrict__ Cf, unsigned short* __restrict__ Ch, int NBX) {
  __shared__ unsigned short As[2][256 * 64];
  __shared__ unsigned short Bs[2][256 * 64];
  const int K = 2048;
  const int nsteps = 32;
  int tid = threadIdx.x;
  int lane = tid & 63;
  int wid = tid >> 6;
  int wm = wid >> 2, wn = wid & 3;
  int l31 = lane & 31, lg2 = lane >> 5;
  int swz = (l31 & 7) << 4;

  int nwg = gridDim.x;
  int cpx = nwg >> 3;
  int sbid = ((int)blockIdx.x & 7) * cpx + ((int)blockIdx.x >> 3);
  int by = sbid / NBX, bx = sbid % NBX;
  int m0 = by * 256, n0 = bx * 256;

  f32x16 acc[4][2] = {};

#define STAGE_A_HALF(tt_, h_, sl_)                                                 \
  do {                                                                             \
    int k0a_ = (tt_) << 6;                                                         \
    _Pragma("unroll") for (int j_ = 0; j_ < 2; ++j_) {                             \
      int L_ = j_ * 8192 + tid * 16;                                               \
      int hr_ = L_ >> 7;                                                           \
      int r_ = (hr_ & 63) + ((hr_ & 64) << 1) + (h_) * 64;                         \
      int cb_ = (L_ & 127) ^ ((r_ & 7) << 4);                                      \
      __builtin_amdgcn_global_load_lds(                                            \
          (const __attribute__((address_space(1))) void*)(A +                      \
              (size_t)(m0 + r_) * K + k0a_ + (cb_ >> 1)),                          \
          (__attribute__((address_space(3))) void*)((char*)&As[sl_][0] +           \
              (h_) * 8192 + j_ * 16384 + tid * 16), 16, 0, 0);                     \
    }                                                                              \
  } while (0)

#define STAGE_B_HALF(tt_, h_, sl_)                                                 \
  do {                                                                             \
    int k0b_ = (tt_) << 6;                                                         \
    _Pragma("unroll") for (int j_ = 0; j_ < 2; ++j_) {                             \
      int L_ = j_ * 8192 + tid * 16;                                               \
      int hr_ = L_ >> 7;                                                           \
      int r_ = (hr_ & 63) + ((hr_ & 64) << 1) + (h_) * 64;                         \
      int cb_ = (L_ & 127) ^ ((r_ & 7) << 4);                                      \
      __builtin_amdgcn_global_load_lds(                                            \
          (const __attribute__((address_space(1))) void*)(B +                      \
              (size_t)(n0 + r_) * K + k0b_ + (cb_ >> 1)),                          \
          (__attribute__((address_space(3))) void*)((char*)&Bs[sl_][0] +           \
              (h_) * 8192 + j_ * 16384 + tid * 16), 16, 0, 0);                     \
    }                                                                              \
  } while (0)

  STAGE_A_HALF(0, 0, 0);
  STAGE_B_HALF(0, 0, 0);
  STAGE_B_HALF(0, 1, 0);
  STAGE_A_HALF(0, 1, 0);
  asm volatile("s_waitcnt vmcnt(0)" ::: "memory");
  __builtin_amdgcn_sched_barrier(0);
  __builtin_amdgcn_s_barrier();

  for (int t = 0; t < nsteps; ++t) {
    int s = t & 1;
    const char* Ab = (const char*)&As[s][0];
    const char* Bb = (const char*)&Bs[s][0];
    half8v afr[2][4], bfr[2][4];
    if (t + 1 < nsteps) {
      STAGE_A_HALF(t + 1, 0, s ^ 1);
      STAGE_B_HALF(t + 1, 0, s ^ 1);
      STAGE_B_HALF(t + 1, 1, s ^ 1);
      STAGE_A_HALF(t + 1, 1, s ^ 1);
    }
#pragma unroll
    for (int ks = 0; ks < 4; ++ks) {
      int cb = (ks * 32 + lg2 * 16) ^ swz;
      afr[0][ks] = *(const half8v*)(Ab + (wm * 128 + 0 + l31) * 128 + cb);
      afr[1][ks] = *(const half8v*)(Ab + (wm * 128 + 32 + l31) * 128 + cb);
      bfr[0][ks] = *(const half8v*)(Bb + (wn * 64 + 0 + l31) * 128 + cb);
      bfr[1][ks] = *(const half8v*)(Bb + (wn * 64 + 32 + l31) * 128 + cb);
    }
    __builtin_amdgcn_s_barrier();
    asm volatile("s_waitcnt lgkmcnt(0)" ::: "memory");
    __builtin_amdgcn_sched_barrier(0);
    __builtin_amdgcn_s_setprio(1);
#pragma unroll
    for (int ks = 0; ks < 4; ++ks) {
      acc[0][0] = __builtin_amdgcn_mfma_f32_32x32x16_f16(afr[0][ks], bfr[0][ks], acc[0][0], 0, 0, 0);
      acc[0][1] = __builtin_amdgcn_mfma_f32_32x32x16_f16(afr[0][ks], bfr[1][ks], acc[0][1], 0, 0, 0);
      acc[1][0] = __builtin_amdgcn_mfma_f32_32x32x16_f16(afr[1][ks], bfr[0][ks], acc[1][0], 0, 0, 0);
      acc[1][1] = __builtin_amdgcn_mfma_f32_32x32x16_f16(afr[1][ks], bfr[1][ks], acc[1][1], 0, 0, 0);
    }
    __builtin_amdgcn_s_setprio(0);
    if (t + 1 < nsteps)
      asm volatile("s_waitcnt vmcnt(8)" ::: "memory");
    else
      asm volatile("s_waitcnt vmcnt(0)" ::: "memory");
    __builtin_amdgcn_sched_barrier(0);
    __builtin_amdgcn_s_barrier();
#pragma unroll
    for (int ks = 0; ks < 4; ++ks) {
      int cb = (ks * 32 + lg2 * 16) ^ swz;
      afr[0][ks] = *(const half8v*)(Ab + (wm * 128 + 64 + l31) * 128 + cb);
      afr[1][ks] = *(const half8v*)(Ab + (wm * 128 + 96 + l31) * 128 + cb);
    }
    __builtin_amdgcn_s_barrier();
    asm volatile("s_waitcnt lgkmcnt(0)" ::: "memory");
    __builtin_amdgcn_sched_barrier(0);
    __builtin_amdgcn_s_setprio(1);
#pragma unroll
    for (int ks = 0; ks < 4; ++ks) {
      acc[2][0] = __builtin_amdgcn_mfma_f32_32x32x16_f16(afr[0][ks], bfr[0][ks], acc[2][0], 0, 0, 0);
      acc[2][1] = __builtin_amdgcn_mfma_f32_32x32x16_f16(afr[0][ks], bfr[1][ks], acc[2][1], 0, 0, 0);
      acc[3][0] = __builtin_amdgcn_mfma_f32_32x32x16_f16(afr[1][ks], bfr[0][ks], acc[3][0], 0, 0, 0);
      acc[3][1] = __builtin_amdgcn_mfma_f32_32x32x16_f16(afr[1][ks], bfr[1][ks], acc[3][1], 0, 0, 0);
    }
    __builtin_amdgcn_s_setprio(0);
    if (t + 1 < nsteps)
      asm volatile("s_waitcnt vmcnt(2)" ::: "memory");
    else
      asm volatile("s_waitcnt vmcnt(0)" ::: "memory");
    __builtin_amdgcn_sched_barrier(0);
    __builtin_amdgcn_s_barrier();
  }
#undef STAGE_A_HALF
#undef STAGE_B_HALF

#pragma unroll
  for (int mi = 0; mi < 4; ++mi) {
#pragma unroll
    for (int ni = 0; ni < 2; ++ni) {
      int col = n0 + wn * 64 + ni * 32 + l31;
#pragma unroll
      for (int r = 0; r < 16; ++r) {
        int row = m0 + wm * 128 + mi * 32 + (r & 3) + 8 * (r >> 2) + 4 * lg2;
        float v = acc[mi][ni][r];
        if (Ch)
          Ch[(size_t)row * 2048 + col] = f2h(v);
        else
          Cf[(size_t)row * 2048 + col] = v;
      }
    }
  }
}

// ---------------- 128x128 fp16 MFMA GEMM for K/V projection ----------------
__global__ __launch_bounds__(256) void gemm_f16_kv_k(
    const unsigned short* __restrict__ A, const unsigned short* __restrict__ B,
    float* __restrict__ Ckv) {
  const int K = 2048;
  __shared__ unsigned short As[128 * 64];
  __shared__ unsigned short Bs[128 * 64];
  int tid = threadIdx.x;
  int lane = tid & 63, wid = tid >> 6;
  int wr = wid >> 1, wc = wid & 1;
  int m0 = blockIdx.y * 128, n0 = blockIdx.x * 128;

  f32x4 acc[4][4] = {};

  int off_ = (wid << 10) + (lane << 4);
  int l15 = lane & 15, lk = lane >> 4;

  for (int t = 0; t < 32; ++t) {
    int k0 = t << 6;
    __syncthreads();
#pragma unroll
    for (int c = 0; c < 4; ++c) {
      int off = off_ + (c << 12);
      int row = off >> 7;
      int cole = (off & 127) >> 1;
      const unsigned short* ga = A + (size_t)(m0 + row) * K + k0 + cole;
      const unsigned short* gb = B + (size_t)(n0 + row) * K + k0 + cole;
      __builtin_amdgcn_global_load_lds(
          (const __attribute__((address_space(1))) void*)ga,
          (__attribute__((address_space(3))) void*)((char*)As + off), 16, 0, 0);
      __builtin_amdgcn_global_load_lds(
          (const __attribute__((address_space(1))) void*)gb,
          (__attribute__((address_space(3))) void*)((char*)Bs + off), 16, 0, 0);
    }
    __syncthreads();
#pragma unroll
    for (int ks = 0; ks < 2; ++ks) {
      half8v af[4], bf[4];
#pragma unroll
      for (int f = 0; f < 4; ++f) {
        int arow = wr * 64 + f * 16 + l15;
        int brow = wc * 64 + f * 16 + l15;
        int colb = ks * 64 + lk * 16;
        af[f] = *(const half8v*)((const char*)As + arow * 128 + colb);
        bf[f] = *(const half8v*)((const char*)Bs + brow * 128 + colb);
      }
#pragma unroll
      for (int fm = 0; fm < 4; ++fm)
#pragma unroll
        for (int fn = 0; fn < 4; ++fn)
          acc[fm][fn] = __builtin_amdgcn_mfma_f32_16x16x32_f16(af[fm], bf[fn], acc[fm][fn], 0, 0, 0);
    }
  }
#pragma unroll
  for (int fm = 0; fm < 4; ++fm) {
#pragma unroll
    for (int j = 0; j < 4; ++j) {
      int row = m0 + wr * 64 + fm * 16 + lk * 4 + j;
#pragma unroll
      for (int fn = 0; fn < 4; ++fn) {
        int col = n0 + wc * 64 + fn * 16 + l15;
        Ckv[(size_t)row * 256 + col] = acc[fm][fn][j];
      }
    }
  }
}

// ---------------- KV transform + minmax (K-RoPE fused; 2 rows/iter) ----------
__global__ __launch_bounds__(256) void kv_transform_k(float* kvb,
                                                      const float* __restrict__ mk,
                                                      const float* __restrict__ mv,
                                                      const float* __restrict__ ct,
                                                      const float* __restrict__ st,
                                                      unsigned* mmx) {
  int which = blockIdx.y;
  float* base = kvb + which * 128;
  const float* M = which ? mv : mk;
  __shared__ float rowb[256];  // 2 rows
  __shared__ float red[256];
  int tid = threadIdx.x;
  int half = tid >> 7, col = tid & 127;
  float vmin = 3.4e38f, vmax = -3.4e38f;
  int r0 = blockIdx.x * 64;
  for (int ri = 0; ri < 32; ri++) {
    size_t row = r0 + ri * 2 + half;
    __syncthreads();
    if (which == 0) {
      int t = (int)(row & (SS - 1));
      int j = col & 63;
      float c = ct[t * 64 + j], s = st[t * 64 + j];
      float x0 = base[row * 256 + j];
      float x1 = base[row * 256 + j + 64];
      rowb[tid] = (col < 64) ? (x0 * c - x1 * s) : (x1 * c + x0 * s);
    } else {
      rowb[tid] = base[row * 256 + col];
    }
    __syncthreads();
    float acc = 0.f;
    const float* rb = &rowb[half * 128];
#pragma unroll 8
    for (int a = 0; a < 128; a++) acc += rb[a] * M[a * 128 + col];
    base[row * 256 + col] = acc;
    vmin = fminf(vmin, acc);
    vmax = fmaxf(vmax, acc);
  }
  red[tid] = vmin;
  __syncthreads();
  for (int s2 = 128; s2 > 0; s2 >>= 1) {
    if (tid < s2) red[tid] = fminf(red[tid], red[tid + s2]);
    __syncthreads();
  }
  if (tid == 0) atomicMin(&mmx[which * 2 + 0], encf(red[0]));
  __syncthreads();
  red[tid] = vmax;
  __syncthreads();
  for (int s2 = 128; s2 > 0; s2 >>= 1) {
    if (tid < s2) red[tid] = fmaxf(red[tid], red[tid + s2]);
    __syncthreads();
  }
  if (tid == 0) atomicMax(&mmx[which * 2 + 1], encf(red[0]));
}

// K codes: qkc[b][s][128] fp16 integers (exact: 0..255)
__global__ void quant_k_codes_k(const float* __restrict__ kvb,
                                unsigned short* __restrict__ qkc,
                                const unsigned* __restrict__ mmx) {
  int i = blockIdx.x * 256 + threadIdx.x;
  float mn = decf(mmx[0]);
  float sc = (decf(mmx[1]) - mn) * (1.f / 255.f);
  int row = i >> 7, d = i & 127;
  float v = kvb[(size_t)row * 256 + d];
  float qv = fminf(fmaxf(rintf((v - mn) / sc), 0.f), 255.f);
  qkc[i] = f2h(qv);
}

// V codes transposed: qvtc[b][d=128][s=2048] fp16 integers
__global__ __launch_bounds__(256) void quant_vt_k(const float* __restrict__ kvb,
                                                  unsigned short* __restrict__ qvtc,
                                                  const unsigned* __restrict__ mmx) {
  int b = blockIdx.y;
  int s0 = blockIdx.x * 64;
  __shared__ unsigned short tile[128 * 72];
  float mn = decf(mmx[2]);
  float sc = (decf(mmx[3]) - mn) * (1.f / 255.f);
  for (int i = threadIdx.x; i < 8192; i += 256) {
    int sl = i >> 7, d = i & 127;
    float v = kvb[((size_t)(b * SS + s0 + sl)) * 256 + 128 + d];
    float qv = fminf(fmaxf(rintf((v - mn) / sc), 0.f), 255.f);
    tile[d * 72 + sl] = f2h(qv);
  }
  __syncthreads();
  int d = threadIdx.x >> 1, hf = threadIdx.x & 1;
  unsigned short* dst = qvtc + (size_t)(b * 128 + d) * 2048 + s0 + hf * 32;
  const unsigned short* srcp = &tile[d * 72 + hf * 32];
#pragma unroll
  for (int u = 0; u < 4; ++u)
    *(ushort4*)(dst + u * 8) = *(const ushort4*)(srcp + u * 8),
    *(ushort4*)(dst + u * 8 + 4) = *(const ushort4*)(srcp + u * 8 + 4);
}

// ---------------- MFMA windowed sigmoid attention (fp16, fused Q-RoPE) --------
// 512 threads / 8 waves. Pair p=w>>1 owns 16 q-rows; EVEN wave computes QK
// (P flows through Pl LDS), both waves split PV across head dim (ohalf=w&1).
// Per-lane acc = 2x16 f32 -> no spill at natural allocation. Rowsums shared
// via dead Ks buffer post-loop. LDS exactly 40960 B.
__global__ __launch_bounds__(512) void attn_mfma_k(
    const unsigned short* __restrict__ qh, const unsigned short* __restrict__ qkc,
    const unsigned short* __restrict__ qvtc, const unsigned* __restrict__ mmx,
    const float* __restrict__ ct, const float* __restrict__ st,
    unsigned short* __restrict__ outp) {
  __shared__ unsigned short Ks[64 * 128];
  __shared__ unsigned short Vt[128 * 64];
  __shared__ unsigned short Pl[64 * 64];
  int tid = threadIdx.x;
  int lane = tid & 63, w = tid >> 6;
  int p = w >> 1, ohalf = w & 1;
  int l15 = lane & 15, lg = lane >> 4;
  int swk = (l15 & 7) << 4;
  int b = blockIdx.y >> 4, h = blockIdx.y & 15;
  int t0 = blockIdx.x * 64;
  int wa = t0 >> 8;

  float mnk = decf(mmx[0]), sck = (decf(mmx[1]) - mnk) * (1.f / 255.f);
  float mnv = decf(mmx[2]), scv = (decf(mmx[3]) - mnv) * (1.f / 255.f);
  float aK = ATT_SCALE * sck;
  float aMnk = ATT_SCALE * mnk;

  half8v qf[4];
  float cj[4];  // ATT_SCALE * mnk * sumQ[row j]   (even waves only)
  if ((w & 1) == 0) {
    int trow = t0 + p * 16 + l15;
    const unsigned short* qrow =
        qh + ((size_t)(b * SS + trow) * NHEADS + h) * HDIM + lg * 8;
    const float* cbp = ct + (size_t)trow * 64 + lg * 8;
    const float* sbp = st + (size_t)trow * 64 + lg * 8;
    float sq = 0.f;
#pragma unroll
    for (int half = 0; half < 2; ++half) {
      half8v xa8 = *(const half8v*)(qrow + half * 32);
      half8v ya8 = *(const half8v*)(qrow + half * 32 + 64);
      float4 ca = *(const float4*)(cbp + half * 32);
      float4 cb4 = *(const float4*)(cbp + half * 32 + 4);
      float4 sa = *(const float4*)(sbp + half * 32);
      float4 sb4 = *(const float4*)(sbp + half * 32 + 4);
      float cv[8] = {ca.x, ca.y, ca.z, ca.w, cb4.x, cb4.y, cb4.z, cb4.w};
      float sv[8] = {sa.x, sa.y, sa.z, sa.w, sb4.x, sb4.y, sb4.z, sb4.w};
      half8v tlo, thi;
#pragma unroll
      for (int u = 0; u < 8; ++u) {
        float xv = (float)xa8[u], yv = (float)ya8[u];
        float r0 = xv * cv[u] - yv * sv[u];
        float r1 = yv * cv[u] + xv * sv[u];
        sq += r0 + r1;
        tlo[u] = (_Float16)r0;
        thi[u] = (_Float16)r1;
      }
      qf[half] = tlo;
      qf[half + 2] = thi;
      __builtin_amdgcn_sched_barrier(0);
    }
    sq += __shfl_xor(sq, 16);
    sq += __shfl_xor(sq, 32);
#pragma unroll
    for (int j = 0; j < 4; ++j) cj[j] = aMnk * __shfl(sq, lg * 4 + j);
  }

  f32x4 zz = {0.f, 0.f, 0.f, 0.f};
  f32x4 acc0[4], acc1[4];
#pragma unroll
  for (int i = 0; i < 4; ++i) { acc0[i] = zz; acc1[i] = zz; }
  float rs0[4] = {0, 0, 0, 0}, rs1[4] = {0, 0, 0, 0};
  int base = wa * 256;

  int n = (wa == 0 || wa == 7) ? 8 : 12;
  int segoff = (wa == 0) ? 1 : 0;
  int kbase = (wa == 0) ? base : base - 256;

#define STAGE_K(K0)                                                                \
  do {                                                                             \
    int k0_ = (K0);                                                                \
    const char* kb_ = (const char*)qkc + ((size_t)b * SS + k0_) * 256;             \
    _Pragma("unroll") for (int i_ = 0; i_ < 2; ++i_) {                             \
      int L_ = i_ * 8192 + tid * 16;                                               \
      int kr_ = L_ >> 8;                                                           \
      int kd_ = (L_ & 255) ^ ((kr_ & 7) << 4);                                     \
      __builtin_amdgcn_global_load_lds(                                            \
          (const __attribute__((address_space(1))) void*)(kb_ + kr_ * 256 + kd_),  \
          (__attribute__((address_space(3))) void*)((char*)Ks + L_), 16, 0, 0);    \
    }                                                                              \
  } while (0)

#define STAGE_V(K0)                                                                \
  do {                                                                             \
    int k0_ = (K0);                                                                \
    const char* vb_ = (const char*)qvtc + (size_t)b * 524288 + (size_t)k0_ * 2;    \
    _Pragma("unroll") for (int i_ = 0; i_ < 2; ++i_) {                             \
      int L_ = i_ * 8192 + tid * 16;                                               \
      int vr_ = L_ >> 7;                                                           \
      int vd_ = (L_ & 127) ^ ((vr_ & 7) << 4);                                     \
      __builtin_amdgcn_global_load_lds(                                            \
          (const __attribute__((address_space(1))) void*)(vb_ + vr_ * 4096 + vd_), \
          (__attribute__((address_space(3))) void*)((char*)Vt + L_), 16, 0, 0);    \
    }                                                                              \
  } while (0)

  STAGE_K(kbase);
  STAGE_V(kbase);
  asm volatile("s_waitcnt vmcnt(2)" ::: "memory");
  __builtin_amdgcn_sched_barrier(0);
  __builtin_amdgcn_s_barrier();

  for (int i = 0; i < n; ++i) {
    int sg = segoff + (i >> 2);
    bool d0 = (sg <= 1) && (wa > 0);
    bool d1 = (sg >= 1);
    // ---------- QK phase (EVEN waves only; reads Ks, writes Pl) ----------
    if ((w & 1) == 0) {
      f32x4 sf0 = zz, sf1 = zz, sf2 = zz, sf3 = zz;
#pragma unroll
      for (int kk = 0; kk < 4; ++kk) {
        int cb = (kk * 64 + lg * 16) ^ swk;
        half8v k0f = *(const half8v*)((const char*)Ks + (0 * 16 + l15) * 256 + cb);
        half8v k1f = *(const half8v*)((const char*)Ks + (1 * 16 + l15) * 256 + cb);
        half8v k2f = *(const half8v*)((const char*)Ks + (2 * 16 + l15) * 256 + cb);
        half8v k3f = *(const half8v*)((const char*)Ks + (3 * 16 + l15) * 256 + cb);
        sf0 = __builtin_amdgcn_mfma_f32_16x16x32_f16(qf[kk], k0f, sf0, 0, 0, 0);
        sf1 = __builtin_amdgcn_mfma_f32_16x16x32_f16(qf[kk], k1f, sf1, 0, 0, 0);
        sf2 = __builtin_amdgcn_mfma_f32_16x16x32_f16(qf[kk], k2f, sf2, 0, 0, 0);
        sf3 = __builtin_amdgcn_mfma_f32_16x16x32_f16(qf[kk], k3f, sf3, 0, 0, 0);
      }
      float rsc[4] = {0.f, 0.f, 0.f, 0.f};
#pragma unroll
      for (int nf = 0; nf < 4; ++nf) {
        f32x4 sv = (nf == 0) ? sf0 : (nf == 1) ? sf1 : (nf == 2) ? sf2 : sf3;
#pragma unroll
        for (int j = 0; j < 4; ++j) {
          float s_ = aK * sv[j] + cj[j];
          float p_ = 1.f / (1.f + __expf(-s_));
          rsc[j] += p_;
          int prow = p * 16 + lg * 4 + j;
          int paddr = prow * 128 + (((nf * 16 + l15) * 2) ^ ((prow & 7) << 4));
          *(unsigned short*)((char*)Pl + paddr) = f2h(p_);
        }
      }
#pragma unroll
      for (int j = 0; j < 4; ++j) {
        rsc[j] += __shfl_xor(rsc[j], 1);
        rsc[j] += __shfl_xor(rsc[j], 2);
        rsc[j] += __shfl_xor(rsc[j], 4);
        rsc[j] += __shfl_xor(rsc[j], 8);
        if (d0) rs0[j] += rsc[j];
        if (d1) rs1[j] += rsc[j];
      }
    }
    __builtin_amdgcn_s_barrier();  // all waves: Ks reads + Pl writes done
    if (i + 1 < n) {
      STAGE_K(kbase + (i + 1) * 64);
      // FIFO: outstanding = V(i) 2 (oldest) + K(i+1) 2 -> waits V(i)
      asm volatile("s_waitcnt vmcnt(2)" ::: "memory");
    } else {
      asm volatile("s_waitcnt vmcnt(0)" ::: "memory");
    }
    __builtin_amdgcn_sched_barrier(0);
    __builtin_amdgcn_s_barrier();  // Vt(i) visible to all waves
    // ---------- PV phase (ALL waves; reads Vt + Pl; dims ohalf*64..) ----------
    {
      half8v pf0, pf1;
      int prow = p * 16 + l15;
      pf0 = *(const half8v*)((const char*)Pl + prow * 128 + ((lg * 16) ^ swk));
      pf1 = *(const half8v*)((const char*)Pl + prow * 128 + ((64 + lg * 16) ^ swk));
#pragma unroll
      for (int nf = 0; nf < 4; ++nf) {
        int dim = ohalf * 64 + nf * 16 + l15;
        int vb0 = dim * 128 + ((lg * 16) ^ swk);
        int vb1 = dim * 128 + ((64 + lg * 16) ^ swk);
        half8v vf0 = *(const half8v*)((const char*)Vt + vb0);
        half8v vf1 = *(const half8v*)((const char*)Vt + vb1);
        if (d0) {
          acc0[nf] = __builtin_amdgcn_mfma_f32_16x16x32_f16(pf0, vf0, acc0[nf], 0, 0, 0);
          acc0[nf] = __builtin_amdgcn_mfma_f32_16x16x32_f16(pf1, vf1, acc0[nf], 0, 0, 0);
        }
        if (d1) {
          acc1[nf] = __builtin_amdgcn_mfma_f32_16x16x32_f16(pf0, vf0, acc1[nf], 0, 0, 0);
          acc1[nf] = __builtin_amdgcn_mfma_f32_16x16x32_f16(pf1, vf1, acc1[nf], 0, 0, 0);
        }
      }
    }
    __builtin_amdgcn_s_barrier();  // all waves done reading Vt (and Pl)
    if (i + 1 < n) {
      STAGE_V(kbase + (i + 1) * 64);
      // FIFO: outstanding = K(i+1) 2 (oldest) + V(i+1) 2 -> waits K(i+1)
      asm volatile("s_waitcnt vmcnt(2)" ::: "memory");
      __builtin_amdgcn_sched_barrier(0);
      __builtin_amdgcn_s_barrier();  // Ks(i+1) visible to all waves
    }
  }
#undef STAGE_K
#undef STAGE_V

  // ---- share rowsums: even waves write into dead Ks buffer, all read ----
  float* rsl = (float*)Ks;  // [2][64] floats; Ks dead (last read >=2 barriers ago)
  if ((w & 1) == 0 && l15 == 0) {
#pragma unroll
    for (int j = 0; j < 4; ++j) {
      rsl[p * 16 + lg * 4 + j] = rs0[j];
      rsl[64 + p * 16 + lg * 4 + j] = rs1[j];
    }
  }
  __syncthreads();

#pragma unroll
  for (int j = 0; j < 4; ++j) {
    int row = p * 16 + lg * 4 + j;
    int t = t0 + row;
    float al = (float)(t & 255) * (1.f / 255.f);
    float r0 = rsl[row], r1 = rsl[64 + row];
    float i0 = 1.f / (r0 + 1e-8f), i1 = 1.f / (r1 + 1e-8f);
    float w0 = (wa == 0) ? 0.f : (1.f - al);
    float w1 = (wa == 0) ? 1.f : al;
    size_t obase = ((size_t)(b * SS + t) * NHEADS + h) * HDIM;
#pragma unroll
    for (int nf = 0; nf < 4; ++nf) {
      float o0 = (scv * acc0[nf][j] + mnv * r0) * i0;
      float o1 = (scv * acc1[nf][j] + mnv * r1) * i1;
      outp[obase + ohalf * 64 + nf * 16 + l15] = f2h(w0 * o0 + w1 * o1);
    }
  }
}

extern "C" void kernel_launch(void* const* d_in, const int* in_sizes, int n_in,
                              void* d_out, int out_size, void* d_ws, size_t ws_size,
                              hipStream_t stream) {
  const float* x = (const float*)d_in[0];
  const float* wq = (const float*)d_in[1];
  const float* wk = (const float*)d_in[2];
  const float* wv = (const float*)d_in[3];
  const float* wo = (const float*)d_in[4];
  const float* kcw = (const float*)d_in[5];
  const float* vcw = (const float*)d_in[6];
  const float* kdw = (const float*)d_in[7];
  const float* vdw = (const float*)d_in[8];
  float* out = (float*)d_out;

  const size_t QN = (size_t)BSROWS * HIDDEN;
  const size_t KVN = (size_t)BSROWS * 256;

  unsigned short* qh = (unsigned short*)d_ws;          // QN fp16 (Q)
  float* kvb = (float*)(qh + QN);                      // KVN fp32
  float* ct = kvb + KVN;
  float* st = ct + SS * 64;
  float* mk = st + SS * 64;
  float* mv = mk + 128 * 128;
  unsigned* mmx = (unsigned*)(mv + 128 * 128);
  unsigned short* xh = (unsigned short*)(mmx + 16);    // QN fp16 (x; later attn out)
  unsigned short* wqkvh = xh + QN;                     // 2304*2048 fp16
  unsigned short* woh = wqkvh + (size_t)2304 * 2048;   // 2048*2048 fp16
  unsigned short* qkc = woh + (size_t)HIDDEN * HIDDEN;
  unsigned short* qvtc = qkc + (size_t)BSROWS * 128;

  rope_tables_k<<<SS, 64, 0, stream>>>(ct, st);
  build_m_k<<<dim3(128, 2), 128, 0, stream>>>(kcw, kdw, vcw, vdw, mk, mv);

  split_fp16_k<<<2048, 256, 0, stream>>>(x, xh, (int)(QN / 4));
  split_fp16_k<<<512, 256, 0, stream>>>(wq, wqkvh, HIDDEN * HIDDEN / 4);
  split_fp16_k<<<256, 256, 0, stream>>>(wk, wqkvh + (size_t)2048 * 2048, HDIM * HIDDEN / 4);
  split_fp16_k<<<256, 256, 0, stream>>>(wv, wqkvh + (size_t)2176 * 2048, HDIM * HIDDEN / 4);
  split_fp16_k<<<512, 256, 0, stream>>>(wo, woh, HIDDEN * HIDDEN / 4);

  // K,V projection: 128^2 fp16 kernel, B rows 2048..2303 of wqkv (grid 2 x 64)
  gemm_f16_kv_k<<<dim3(2, 64), 256, 0, stream>>>(xh, wqkvh + (size_t)2048 * 2048, kvb);
  // Q = x @ wq^T : fp16 output
  gemm_f16_ph_k<<<256, 512, 0, stream>>>(xh, wqkvh, nullptr, qh, 8);

  // KV low-rank transform (K-RoPE fused at load) + global minmax
  mm_init_k<<<1, 64, 0, stream>>>(mmx);
  kv_transform_k<<<dim3(BSROWS / 64, 2), 256, 0, stream>>>(kvb, mk, mv, ct, st, mmx);
  quant_k_codes_k<<<(BSROWS * 128) / 256, 256, 0, stream>>>(kvb, qkc, mmx);
  quant_vt_k<<<dim3(SS / 64, BB), 256, 0, stream>>>(kvb, qvtc, mmx);

  // attention (fused Q-RoPE, fp16 Q) writes fp16 output into xh (x is dead here)
  attn_mfma_k<<<dim3(SS / 64, BB * NHEADS), 512, 0, stream>>>(qh, qkc, qvtc, mmx, ct, st,
                                                              xh);

  // out = attn @ wo^T : fp32 output
  gemm_f16_ph_k<<<256, 512, 0, stream>>>(xh, woh, out, nullptr, 8);
}

// Round 20
// 554.192 us; speedup vs baseline: 1.1751x; 1.1751x over previous
//
#include <hip/hip_runtime.h>
#include <hip/hip_bf16.h>
#include <hip/hip_fp16.h>
#include <math.h>

#define BB 4
#define SS 2048
#define HIDDEN 2048
#define NHEADS 16
#define HDIM 128
#define BSROWS (BB * SS)
#define ATT_SCALE 0.08838834764831845f

typedef __attribute__((ext_vector_type(8))) _Float16 half8v;
typedef __attribute__((ext_vector_type(4))) float f32x4;
typedef __attribute__((ext_vector_type(16))) float f32x16;

static __device__ __forceinline__ unsigned encf(float x) {
  unsigned b = __float_as_uint(x);
  return (b & 0x80000000u) ? ~b : (b | 0x80000000u);
}
static __device__ __forceinline__ float decf(unsigned k) {
  unsigned b = (k & 0x80000000u) ? (k ^ 0x80000000u) : ~k;
  return __uint_as_float(b);
}
static __device__ __forceinline__ unsigned short f2h(float f) {
  _Float16 h = (_Float16)f;  // v_cvt_f16_f32, RNE
  return *(unsigned short*)&h;
}

// ---------------- small setup kernels ----------------

__global__ void rope_tables_k(float* __restrict__ ct, float* __restrict__ st) {
  int t = blockIdx.x;
  int d = threadIdx.x;  // 0..63
  float inv = powf(10000.0f, -(float)d * (1.0f / 64.0f));
  float a = (float)t * inv;
  ct[t * 64 + d] = cosf(a);
  st[t * 64 + d] = sinf(a);
}

__global__ void build_m_k(const float* __restrict__ kc, const float* __restrict__ kdw,
                          const float* __restrict__ vc, const float* __restrict__ vdw,
                          float* __restrict__ mk, float* __restrict__ mv) {
  int a = blockIdx.x;
  int c = threadIdx.x;
  const float* cw = blockIdx.y ? vc : kc;
  const float* dw = blockIdx.y ? vdw : kdw;
  float* m = blockIdx.y ? mv : mk;
  float acc = 0.f;
#pragma unroll
  for (int mm = 0; mm < 32; mm++) acc += cw[mm * 128 + a] * dw[c * 32 + mm];
  m[a * 128 + c] = acc;
}

__global__ void mm_init_k(unsigned* mmx) {
  int i = threadIdx.x;
  if (i < 4) mmx[i] = (i & 1) ? 0u : 0xFFFFFFFFu;
}

// fp32 -> fp16
__global__ void split_fp16_k(const float* __restrict__ src,
                             unsigned short* __restrict__ hi, int n4) {
  int i = blockIdx.x * 256 + threadIdx.x;
  int stride = gridDim.x * 256;
  for (; i < n4; i += stride) {
    float4 v = ((const float4*)src)[i];
    ((ushort4*)hi)[i] = make_ushort4(f2h(v.x), f2h(v.y), f2h(v.z), f2h(v.w));
  }
}

// ---------------- 256x256 deep-pipelined fp16 MFMA GEMM ----------------
// (r15-proven) All 4 half-tiles of t+1 staged at top of ph1(t); vmcnt(8)
// before ph2, vmcnt(2) at tile end. Output fp32 Cf or fp16 Ch.
__global__ __launch_bounds__(512, 2) void gemm_f16_ph_k(
    const unsigned short* __restrict__ A, const unsigned short* __restrict__ B,
    float* __restrict__ Cf, unsigned short* __restrict__ Ch, int NBX) {
  __shared__ unsigned short As[2][256 * 64];
  __shared__ unsigned short Bs[2][256 * 64];
  const int K = 2048;
  const int nsteps = 32;
  int tid = threadIdx.x;
  int lane = tid & 63;
  int wid = tid >> 6;
  int wm = wid >> 2, wn = wid & 3;
  int l31 = lane & 31, lg2 = lane >> 5;
  int swz = (l31 & 7) << 4;

  int nwg = gridDim.x;
  int cpx = nwg >> 3;
  int sbid = ((int)blockIdx.x & 7) * cpx + ((int)blockIdx.x >> 3);
  int by = sbid / NBX, bx = sbid % NBX;
  int m0 = by * 256, n0 = bx * 256;

  f32x16 acc[4][2] = {};

#define STAGE_A_HALF(tt_, h_, sl_)                                                 \
  do {                                                                             \
    int k0a_ = (tt_) << 6;                                                         \
    _Pragma("unroll") for (int j_ = 0; j_ < 2; ++j_) {                             \
      int L_ = j_ * 8192 + tid * 16;                                               \
      int hr_ = L_ >> 7;                                                           \
      int r_ = (hr_ & 63) + ((hr_ & 64) << 1) + (h_) * 64;                         \
      int cb_ = (L_ & 127) ^ ((r_ & 7) << 4);                                      \
      __builtin_amdgcn_global_load_lds(                                            \
          (const __attribute__((address_space(1))) void*)(A +                      \
              (size_t)(m0 + r_) * K + k0a_ + (cb_ >> 1)),                          \
          (__attribute__((address_space(3))) void*)((char*)&As[sl_][0] +           \
              (h_) * 8192 + j_ * 16384 + tid * 16), 16, 0, 0);                     \
    }                                                                              \
  } while (0)

#define STAGE_B_HALF(tt_, h_, sl_)                                                 \
  do {                                                                             \
    int k0b_ = (tt_) << 6;                                                         \
    _Pragma("unroll") for (int j_ = 0; j_ < 2; ++j_) {                             \
      int L_ = j_ * 8192 + tid * 16;                                               \
      int hr_ = L_ >> 7;                                                           \
      int r_ = (hr_ & 63) + ((hr_ & 64) << 1) + (h_) * 64;                         \
      int cb_ = (L_ & 127) ^ ((r_ & 7) << 4);                                      \
      __builtin_amdgcn_global_load_lds(                                            \
          (const __attribute__((address_space(1))) void*)(B +                      \
              (size_t)(n0 + r_) * K + k0b_ + (cb_ >> 1)),                          \
          (__attribute__((address_space(3))) void*)((char*)&Bs[sl_][0] +           \
              (h_) * 8192 + j_ * 16384 + tid * 16), 16, 0, 0);                     \
    }                                                                              \
  } while (0)

  STAGE_A_HALF(0, 0, 0);
  STAGE_B_HALF(0, 0, 0);
  STAGE_B_HALF(0, 1, 0);
  STAGE_A_HALF(0, 1, 0);
  asm volatile("s_waitcnt vmcnt(0)" ::: "memory");
  __builtin_amdgcn_sched_barrier(0);
  __builtin_amdgcn_s_barrier();

  for (int t = 0; t < nsteps; ++t) {
    int s = t & 1;
    const char* Ab = (const char*)&As[s][0];
    const char* Bb = (const char*)&Bs[s][0];
    half8v afr[2][4], bfr[2][4];
    if (t + 1 < nsteps) {
      STAGE_A_HALF(t + 1, 0, s ^ 1);
      STAGE_B_HALF(t + 1, 0, s ^ 1);
      STAGE_B_HALF(t + 1, 1, s ^ 1);
      STAGE_A_HALF(t + 1, 1, s ^ 1);
    }
#pragma unroll
    for (int ks = 0; ks < 4; ++ks) {
      int cb = (ks * 32 + lg2 * 16) ^ swz;
      afr[0][ks] = *(const half8v*)(Ab + (wm * 128 + 0 + l31) * 128 + cb);
      afr[1][ks] = *(const half8v*)(Ab + (wm * 128 + 32 + l31) * 128 + cb);
      bfr[0][ks] = *(const half8v*)(Bb + (wn * 64 + 0 + l31) * 128 + cb);
      bfr[1][ks] = *(const half8v*)(Bb + (wn * 64 + 32 + l31) * 128 + cb);
    }
    __builtin_amdgcn_s_barrier();
    asm volatile("s_waitcnt lgkmcnt(0)" ::: "memory");
    __builtin_amdgcn_sched_barrier(0);
    __builtin_amdgcn_s_setprio(1);
#pragma unroll
    for (int ks = 0; ks < 4; ++ks) {
      acc[0][0] = __builtin_amdgcn_mfma_f32_32x32x16_f16(afr[0][ks], bfr[0][ks], acc[0][0], 0, 0, 0);
      acc[0][1] = __builtin_amdgcn_mfma_f32_32x32x16_f16(afr[0][ks], bfr[1][ks], acc[0][1], 0, 0, 0);
      acc[1][0] = __builtin_amdgcn_mfma_f32_32x32x16_f16(afr[1][ks], bfr[0][ks], acc[1][0], 0, 0, 0);
      acc[1][1] = __builtin_amdgcn_mfma_f32_32x32x16_f16(afr[1][ks], bfr[1][ks], acc[1][1], 0, 0, 0);
    }
    __builtin_amdgcn_s_setprio(0);
    if (t + 1 < nsteps)
      asm volatile("s_waitcnt vmcnt(8)" ::: "memory");
    else
      asm volatile("s_waitcnt vmcnt(0)" ::: "memory");
    __builtin_amdgcn_sched_barrier(0);
    __builtin_amdgcn_s_barrier();
#pragma unroll
    for (int ks = 0; ks < 4; ++ks) {
      int cb = (ks * 32 + lg2 * 16) ^ swz;
      afr[0][ks] = *(const half8v*)(Ab + (wm * 128 + 64 + l31) * 128 + cb);
      afr[1][ks] = *(const half8v*)(Ab + (wm * 128 + 96 + l31) * 128 + cb);
    }
    __builtin_amdgcn_s_barrier();
    asm volatile("s_waitcnt lgkmcnt(0)" ::: "memory");
    __builtin_amdgcn_sched_barrier(0);
    __builtin_amdgcn_s_setprio(1);
#pragma unroll
    for (int ks = 0; ks < 4; ++ks) {
      acc[2][0] = __builtin_amdgcn_mfma_f32_32x32x16_f16(afr[0][ks], bfr[0][ks], acc[2][0], 0, 0, 0);
      acc[2][1] = __builtin_amdgcn_mfma_f32_32x32x16_f16(afr[0][ks], bfr[1][ks], acc[2][1], 0, 0, 0);
      acc[3][0] = __builtin_amdgcn_mfma_f32_32x32x16_f16(afr[1][ks], bfr[0][ks], acc[3][0], 0, 0, 0);
      acc[3][1] = __builtin_amdgcn_mfma_f32_32x32x16_f16(afr[1][ks], bfr[1][ks], acc[3][1], 0, 0, 0);
    }
    __builtin_amdgcn_s_setprio(0);
    if (t + 1 < nsteps)
      asm volatile("s_waitcnt vmcnt(2)" ::: "memory");
    else
      asm volatile("s_waitcnt vmcnt(0)" ::: "memory");
    __builtin_amdgcn_sched_barrier(0);
    __builtin_amdgcn_s_barrier();
  }
#undef STAGE_A_HALF
#undef STAGE_B_HALF

#pragma unroll
  for (int mi = 0; mi < 4; ++mi) {
#pragma unroll
    for (int ni = 0; ni < 2; ++ni) {
      int col = n0 + wn * 64 + ni * 32 + l31;
#pragma unroll
      for (int r = 0; r < 16; ++r) {
        int row = m0 + wm * 128 + mi * 32 + (r & 3) + 8 * (r >> 2) + 4 * lg2;
        float v = acc[mi][ni][r];
        if (Ch)
          Ch[(size_t)row * 2048 + col] = f2h(v);
        else
          Cf[(size_t)row * 2048 + col] = v;
      }
    }
  }
}

// ---------------- 128x128 fp16 MFMA GEMM for K/V projection ----------------
__global__ __launch_bounds__(256) void gemm_f16_kv_k(
    const unsigned short* __restrict__ A, const unsigned short* __restrict__ B,
    float* __restrict__ Ckv) {
  const int K = 2048;
  __shared__ unsigned short As[128 * 64];
  __shared__ unsigned short Bs[128 * 64];
  int tid = threadIdx.x;
  int lane = tid & 63, wid = tid >> 6;
  int wr = wid >> 1, wc = wid & 1;
  int m0 = blockIdx.y * 128, n0 = blockIdx.x * 128;

  f32x4 acc[4][4] = {};

  int off_ = (wid << 10) + (lane << 4);
  int l15 = lane & 15, lk = lane >> 4;

  for (int t = 0; t < 32; ++t) {
    int k0 = t << 6;
    __syncthreads();
#pragma unroll
    for (int c = 0; c < 4; ++c) {
      int off = off_ + (c << 12);
      int row = off >> 7;
      int cole = (off & 127) >> 1;
      const unsigned short* ga = A + (size_t)(m0 + row) * K + k0 + cole;
      const unsigned short* gb = B + (size_t)(n0 + row) * K + k0 + cole;
      __builtin_amdgcn_global_load_lds(
          (const __attribute__((address_space(1))) void*)ga,
          (__attribute__((address_space(3))) void*)((char*)As + off), 16, 0, 0);
      __builtin_amdgcn_global_load_lds(
          (const __attribute__((address_space(1))) void*)gb,
          (__attribute__((address_space(3))) void*)((char*)Bs + off), 16, 0, 0);
    }
    __syncthreads();
#pragma unroll
    for (int ks = 0; ks < 2; ++ks) {
      half8v af[4], bf[4];
#pragma unroll
      for (int f = 0; f < 4; ++f) {
        int arow = wr * 64 + f * 16 + l15;
        int brow = wc * 64 + f * 16 + l15;
        int colb = ks * 64 + lk * 16;
        af[f] = *(const half8v*)((const char*)As + arow * 128 + colb);
        bf[f] = *(const half8v*)((const char*)Bs + brow * 128 + colb);
      }
#pragma unroll
      for (int fm = 0; fm < 4; ++fm)
#pragma unroll
        for (int fn = 0; fn < 4; ++fn)
          acc[fm][fn] = __builtin_amdgcn_mfma_f32_16x16x32_f16(af[fm], bf[fn], acc[fm][fn], 0, 0, 0);
    }
  }
#pragma unroll
  for (int fm = 0; fm < 4; ++fm) {
#pragma unroll
    for (int j = 0; j < 4; ++j) {
      int row = m0 + wr * 64 + fm * 16 + lk * 4 + j;
#pragma unroll
      for (int fn = 0; fn < 4; ++fn) {
        int col = n0 + wc * 64 + fn * 16 + l15;
        Ckv[(size_t)row * 256 + col] = acc[fm][fn][j];
      }
    }
  }
}

// ---------------- KV transform + minmax (K-RoPE fused; 2 rows/iter) ----------
__global__ __launch_bounds__(256) void kv_transform_k(float* kvb,
                                                      const float* __restrict__ mk,
                                                      const float* __restrict__ mv,
                                                      const float* __restrict__ ct,
                                                      const float* __restrict__ st,
                                                      unsigned* mmx) {
  int which = blockIdx.y;
  float* base = kvb + which * 128;
  const float* M = which ? mv : mk;
  __shared__ float rowb[256];  // 2 rows
  __shared__ float red[256];
  int tid = threadIdx.x;
  int half = tid >> 7, col = tid & 127;
  float vmin = 3.4e38f, vmax = -3.4e38f;
  int r0 = blockIdx.x * 64;
  for (int ri = 0; ri < 32; ri++) {
    size_t row = r0 + ri * 2 + half;
    __syncthreads();
    if (which == 0) {
      int t = (int)(row & (SS - 1));
      int j = col & 63;
      float c = ct[t * 64 + j], s = st[t * 64 + j];
      float x0 = base[row * 256 + j];
      float x1 = base[row * 256 + j + 64];
      rowb[tid] = (col < 64) ? (x0 * c - x1 * s) : (x1 * c + x0 * s);
    } else {
      rowb[tid] = base[row * 256 + col];
    }
    __syncthreads();
    float acc = 0.f;
    const float* rb = &rowb[half * 128];
#pragma unroll 8
    for (int a = 0; a < 128; a++) acc += rb[a] * M[a * 128 + col];
    base[row * 256 + col] = acc;
    vmin = fminf(vmin, acc);
    vmax = fmaxf(vmax, acc);
  }
  red[tid] = vmin;
  __syncthreads();
  for (int s2 = 128; s2 > 0; s2 >>= 1) {
    if (tid < s2) red[tid] = fminf(red[tid], red[tid + s2]);
    __syncthreads();
  }
  if (tid == 0) atomicMin(&mmx[which * 2 + 0], encf(red[0]));
  __syncthreads();
  red[tid] = vmax;
  __syncthreads();
  for (int s2 = 128; s2 > 0; s2 >>= 1) {
    if (tid < s2) red[tid] = fmaxf(red[tid], red[tid + s2]);
    __syncthreads();
  }
  if (tid == 0) atomicMax(&mmx[which * 2 + 1], encf(red[0]));
}

// K codes: qkc[b][s][128] fp16 integers (exact: 0..255)
__global__ void quant_k_codes_k(const float* __restrict__ kvb,
                                unsigned short* __restrict__ qkc,
                                const unsigned* __restrict__ mmx) {
  int i = blockIdx.x * 256 + threadIdx.x;
  float mn = decf(mmx[0]);
  float sc = (decf(mmx[1]) - mn) * (1.f / 255.f);
  int row = i >> 7, d = i & 127;
  float v = kvb[(size_t)row * 256 + d];
  float qv = fminf(fmaxf(rintf((v - mn) / sc), 0.f), 255.f);
  qkc[i] = f2h(qv);
}

// V codes transposed: qvtc[b][d=128][s=2048] fp16 integers
__global__ __launch_bounds__(256) void quant_vt_k(const float* __restrict__ kvb,
                                                  unsigned short* __restrict__ qvtc,
                                                  const unsigned* __restrict__ mmx) {
  int b = blockIdx.y;
  int s0 = blockIdx.x * 64;
  __shared__ unsigned short tile[128 * 72];
  float mn = decf(mmx[2]);
  float sc = (decf(mmx[3]) - mn) * (1.f / 255.f);
  for (int i = threadIdx.x; i < 8192; i += 256) {
    int sl = i >> 7, d = i & 127;
    float v = kvb[((size_t)(b * SS + s0 + sl)) * 256 + 128 + d];
    float qv = fminf(fmaxf(rintf((v - mn) / sc), 0.f), 255.f);
    tile[d * 72 + sl] = f2h(qv);
  }
  __syncthreads();
  int d = threadIdx.x >> 1, hf = threadIdx.x & 1;
  unsigned short* dst = qvtc + (size_t)(b * 128 + d) * 2048 + s0 + hf * 32;
  const unsigned short* srcp = &tile[d * 72 + hf * 32];
#pragma unroll
  for (int u = 0; u < 4; ++u)
    *(ushort4*)(dst + u * 8) = *(const ushort4*)(srcp + u * 8),
    *(ushort4*)(dst + u * 8 + 4) = *(const ushort4*)(srcp + u * 8 + 4);
}

// ---------------- MFMA windowed sigmoid attention (fp16, fused Q-RoPE) --------
// r12/r16/r18-proven config: __launch_bounds__(256,3), 84-VGPR spill codegen.
// Empirical A/B matrix: 84-VGPR spill (190us) beats spill-free 148-VGPR
// (299us), 3-segment (493us), and 512-thr wave-split (284us). Keep exactly.
__global__ __launch_bounds__(256, 3) void attn_mfma_k(
    const unsigned short* __restrict__ qh, const unsigned short* __restrict__ qkc,
    const unsigned short* __restrict__ qvtc, const unsigned* __restrict__ mmx,
    const float* __restrict__ ct, const float* __restrict__ st,
    unsigned short* __restrict__ outp) {
  __shared__ unsigned short Ks[64 * 128];
  __shared__ unsigned short Vt[128 * 64];
  __shared__ unsigned short Pl[64 * 64];
  int tid = threadIdx.x;
  int lane = tid & 63, w = tid >> 6;
  int l15 = lane & 15, lg = lane >> 4;
  int swk = (l15 & 7) << 4;
  int b = blockIdx.y >> 4, h = blockIdx.y & 15;
  int t0 = blockIdx.x * 64;
  int wa = t0 >> 8;

  float mnk = decf(mmx[0]), sck = (decf(mmx[1]) - mnk) * (1.f / 255.f);
  float mnv = decf(mmx[2]), scv = (decf(mmx[3]) - mnv) * (1.f / 255.f);
  float aK = ATT_SCALE * sck;
  float aMnk = ATT_SCALE * mnk;

  half8v qf[4];
  float cj[4];  // ATT_SCALE * mnk * sumQ[row j]
  {
    int trow = t0 + w * 16 + l15;
    const unsigned short* qrow =
        qh + ((size_t)(b * SS + trow) * NHEADS + h) * HDIM + lg * 8;
    const float* cbp = ct + (size_t)trow * 64 + lg * 8;
    const float* sbp = st + (size_t)trow * 64 + lg * 8;
    float sq = 0.f;
#pragma unroll
    for (int half = 0; half < 2; ++half) {
      half8v xa8 = *(const half8v*)(qrow + half * 32);
      half8v ya8 = *(const half8v*)(qrow + half * 32 + 64);
      float4 ca = *(const float4*)(cbp + half * 32);
      float4 cb4 = *(const float4*)(cbp + half * 32 + 4);
      float4 sa = *(const float4*)(sbp + half * 32);
      float4 sb4 = *(const float4*)(sbp + half * 32 + 4);
      float cv[8] = {ca.x, ca.y, ca.z, ca.w, cb4.x, cb4.y, cb4.z, cb4.w};
      float sv[8] = {sa.x, sa.y, sa.z, sa.w, sb4.x, sb4.y, sb4.z, sb4.w};
      half8v tlo, thi;
#pragma unroll
      for (int u = 0; u < 8; ++u) {
        float xv = (float)xa8[u], yv = (float)ya8[u];
        float r0 = xv * cv[u] - yv * sv[u];
        float r1 = yv * cv[u] + xv * sv[u];
        sq += r0 + r1;
        tlo[u] = (_Float16)r0;
        thi[u] = (_Float16)r1;
      }
      qf[half] = tlo;
      qf[half + 2] = thi;
      __builtin_amdgcn_sched_barrier(0);
    }
    sq += __shfl_xor(sq, 16);
    sq += __shfl_xor(sq, 32);
#pragma unroll
    for (int j = 0; j < 4; ++j) cj[j] = aMnk * __shfl(sq, lg * 4 + j);
  }

  f32x4 zz = {0.f, 0.f, 0.f, 0.f};
  f32x4 acc0[8], acc1[8];
#pragma unroll
  for (int i = 0; i < 8; ++i) { acc0[i] = zz; acc1[i] = zz; }
  float rs0[4] = {0, 0, 0, 0}, rs1[4] = {0, 0, 0, 0};
  int base = wa * 256;

  int n = (wa == 0 || wa == 7) ? 8 : 12;
  int segoff = (wa == 0) ? 1 : 0;
  int kbase = (wa == 0) ? base : base - 256;

#define STAGE_K(K0)                                                                \
  do {                                                                             \
    int k0_ = (K0);                                                                \
    const char* kb_ = (const char*)qkc + ((size_t)b * SS + k0_) * 256;             \
    _Pragma("unroll") for (int i_ = 0; i_ < 4; ++i_) {                             \
      int L_ = w * 4096 + i_ * 1024 + lane * 16;                                   \
      int kr_ = L_ >> 8;                                                           \
      int kd_ = (L_ & 255) ^ ((kr_ & 7) << 4);                                     \
      __builtin_amdgcn_global_load_lds(                                            \
          (const __attribute__((address_space(1))) void*)(kb_ + kr_ * 256 + kd_),  \
          (__attribute__((address_space(3))) void*)((char*)Ks + L_), 16, 0, 0);    \
    }                                                                              \
  } while (0)

#define STAGE_V(K0)                                                                \
  do {                                                                             \
    int k0_ = (K0);                                                                \
    const char* vb_ = (const char*)qvtc + (size_t)b * 524288 + (size_t)k0_ * 2;    \
    _Pragma("unroll") for (int i_ = 0; i_ < 4; ++i_) {                             \
      int L_ = w * 4096 + i_ * 1024 + lane * 16;                                   \
      int vr_ = L_ >> 7;                                                           \
      int vd_ = (L_ & 127) ^ ((vr_ & 7) << 4);                                     \
      __builtin_amdgcn_global_load_lds(                                            \
          (const __attribute__((address_space(1))) void*)(vb_ + vr_ * 4096 + vd_), \
          (__attribute__((address_space(3))) void*)((char*)Vt + L_), 16, 0, 0);    \
    }                                                                              \
  } while (0)

  STAGE_K(kbase);
  STAGE_V(kbase);
  asm volatile("s_waitcnt vmcnt(4)" ::: "memory");
  __builtin_amdgcn_sched_barrier(0);
  __builtin_amdgcn_s_barrier();

  for (int i = 0; i < n; ++i) {
    int sg = segoff + (i >> 2);
    bool d0 = (sg <= 1) && (wa > 0);
    bool d1 = (sg >= 1);
    // ---------- QK phase (reads Ks) ----------
    {
      f32x4 sf0 = zz, sf1 = zz, sf2 = zz, sf3 = zz;
#pragma unroll
      for (int kk = 0; kk < 4; ++kk) {
        int cb = (kk * 64 + lg * 16) ^ swk;
        half8v k0f = *(const half8v*)((const char*)Ks + (0 * 16 + l15) * 256 + cb);
        half8v k1f = *(const half8v*)((const char*)Ks + (1 * 16 + l15) * 256 + cb);
        half8v k2f = *(const half8v*)((const char*)Ks + (2 * 16 + l15) * 256 + cb);
        half8v k3f = *(const half8v*)((const char*)Ks + (3 * 16 + l15) * 256 + cb);
        sf0 = __builtin_amdgcn_mfma_f32_16x16x32_f16(qf[kk], k0f, sf0, 0, 0, 0);
        sf1 = __builtin_amdgcn_mfma_f32_16x16x32_f16(qf[kk], k1f, sf1, 0, 0, 0);
        sf2 = __builtin_amdgcn_mfma_f32_16x16x32_f16(qf[kk], k2f, sf2, 0, 0, 0);
        sf3 = __builtin_amdgcn_mfma_f32_16x16x32_f16(qf[kk], k3f, sf3, 0, 0, 0);
      }
      float rsc[4] = {0.f, 0.f, 0.f, 0.f};
#pragma unroll
      for (int nf = 0; nf < 4; ++nf) {
        f32x4 sv = (nf == 0) ? sf0 : (nf == 1) ? sf1 : (nf == 2) ? sf2 : sf3;
#pragma unroll
        for (int j = 0; j < 4; ++j) {
          float s_ = aK * sv[j] + cj[j];
          float p_ = 1.f / (1.f + __expf(-s_));
          rsc[j] += p_;
          int prow = w * 16 + lg * 4 + j;
          int paddr = prow * 128 + (((nf * 16 + l15) * 2) ^ ((prow & 7) << 4));
          *(unsigned short*)((char*)Pl + paddr) = f2h(p_);
        }
      }
#pragma unroll
      for (int j = 0; j < 4; ++j) {
        rsc[j] += __shfl_xor(rsc[j], 1);
        rsc[j] += __shfl_xor(rsc[j], 2);
        rsc[j] += __shfl_xor(rsc[j], 4);
        rsc[j] += __shfl_xor(rsc[j], 8);
        if (d0) rs0[j] += rsc[j];
        if (d1) rs1[j] += rsc[j];
      }
    }
    __builtin_amdgcn_s_barrier();  // all waves done reading Ks
    if (i + 1 < n) {
      STAGE_K(kbase + (i + 1) * 64);
      asm volatile("s_waitcnt vmcnt(4)" ::: "memory");
    } else {
      asm volatile("s_waitcnt vmcnt(0)" ::: "memory");
    }
    __builtin_amdgcn_sched_barrier(0);
    __builtin_amdgcn_s_barrier();  // Vt(i) visible to all waves
    // ---------- PV phase (reads Vt + Pl) ----------
    {
      half8v pf0, pf1;
      int prow = w * 16 + l15;
      pf0 = *(const half8v*)((const char*)Pl + prow * 128 + ((lg * 16) ^ swk));
      pf1 = *(const half8v*)((const char*)Pl + prow * 128 + ((64 + lg * 16) ^ swk));
#pragma unroll
      for (int nf = 0; nf < 8; ++nf) {
        int vb0 = (nf * 16 + l15) * 128 + ((lg * 16) ^ swk);
        int vb1 = (nf * 16 + l15) * 128 + ((64 + lg * 16) ^ swk);
        half8v vf0 = *(const half8v*)((const char*)Vt + vb0);
        half8v vf1 = *(const half8v*)((const char*)Vt + vb1);
        if (d0) {
          acc0[nf] = __builtin_amdgcn_mfma_f32_16x16x32_f16(pf0, vf0, acc0[nf], 0, 0, 0);
          acc0[nf] = __builtin_amdgcn_mfma_f32_16x16x32_f16(pf1, vf1, acc0[nf], 0, 0, 0);
        }
        if (d1) {
          acc1[nf] = __builtin_amdgcn_mfma_f32_16x16x32_f16(pf0, vf0, acc1[nf], 0, 0, 0);
          acc1[nf] = __builtin_amdgcn_mfma_f32_16x16x32_f16(pf1, vf1, acc1[nf], 0, 0, 0);
        }
      }
    }
    __builtin_amdgcn_s_barrier();  // all waves done reading Vt
    if (i + 1 < n) {
      STAGE_V(kbase + (i + 1) * 64);
      asm volatile("s_waitcnt vmcnt(4)" ::: "memory");
      __builtin_amdgcn_sched_barrier(0);
      __builtin_amdgcn_s_barrier();  // Ks(i+1) visible to all waves
    }
  }
#undef STAGE_K
#undef STAGE_V

#pragma unroll
  for (int j = 0; j < 4; ++j) {
    int t = t0 + w * 16 + lg * 4 + j;
    float al = (float)(t & 255) * (1.f / 255.f);
    float r0 = rs0[j], r1 = rs1[j];
    float i0 = 1.f / (r0 + 1e-8f), i1 = 1.f / (r1 + 1e-8f);
    float w0 = (wa == 0) ? 0.f : (1.f - al);
    float w1 = (wa == 0) ? 1.f : al;
    size_t obase = ((size_t)(b * SS + t) * NHEADS + h) * HDIM;
#pragma unroll
    for (int nf = 0; nf < 8; ++nf) {
      float o0 = (scv * acc0[nf][j] + mnv * r0) * i0;
      float o1 = (scv * acc1[nf][j] + mnv * r1) * i1;
      outp[obase + nf * 16 + l15] = f2h(w0 * o0 + w1 * o1);
    }
  }
}

extern "C" void kernel_launch(void* const* d_in, const int* in_sizes, int n_in,
                              void* d_out, int out_size, void* d_ws, size_t ws_size,
                              hipStream_t stream) {
  const float* x = (const float*)d_in[0];
  const float* wq = (const float*)d_in[1];
  const float* wk = (const float*)d_in[2];
  const float* wv = (const float*)d_in[3];
  const float* wo = (const float*)d_in[4];
  const float* kcw = (const float*)d_in[5];
  const float* vcw = (const float*)d_in[6];
  const float* kdw = (const float*)d_in[7];
  const float* vdw = (const float*)d_in[8];
  float* out = (float*)d_out;

  const size_t QN = (size_t)BSROWS * HIDDEN;
  const size_t KVN = (size_t)BSROWS * 256;

  unsigned short* qh = (unsigned short*)d_ws;          // QN fp16 (Q)
  float* kvb = (float*)(qh + QN);                      // KVN fp32
  float* ct = kvb + KVN;
  float* st = ct + SS * 64;
  float* mk = st + SS * 64;
  float* mv = mk + 128 * 128;
  unsigned* mmx = (unsigned*)(mv + 128 * 128);
  unsigned short* xh = (unsigned short*)(mmx + 16);    // QN fp16 (x; later attn out)
  unsigned short* wqkvh = xh + QN;                     // 2304*2048 fp16
  unsigned short* woh = wqkvh + (size_t)2304 * 2048;   // 2048*2048 fp16
  unsigned short* qkc = woh + (size_t)HIDDEN * HIDDEN;
  unsigned short* qvtc = qkc + (size_t)BSROWS * 128;

  rope_tables_k<<<SS, 64, 0, stream>>>(ct, st);
  build_m_k<<<dim3(128, 2), 128, 0, stream>>>(kcw, kdw, vcw, vdw, mk, mv);

  split_fp16_k<<<2048, 256, 0, stream>>>(x, xh, (int)(QN / 4));
  split_fp16_k<<<512, 256, 0, stream>>>(wq, wqkvh, HIDDEN * HIDDEN / 4);
  split_fp16_k<<<256, 256, 0, stream>>>(wk, wqkvh + (size_t)2048 * 2048, HDIM * HIDDEN / 4);
  split_fp16_k<<<256, 256, 0, stream>>>(wv, wqkvh + (size_t)2176 * 2048, HDIM * HIDDEN / 4);
  split_fp16_k<<<512, 256, 0, stream>>>(wo, woh, HIDDEN * HIDDEN / 4);

  // K,V projection: 128^2 fp16 kernel, B rows 2048..2303 of wqkv (grid 2 x 64)
  gemm_f16_kv_k<<<dim3(2, 64), 256, 0, stream>>>(xh, wqkvh + (size_t)2048 * 2048, kvb);
  // Q = x @ wq^T : fp16 output
  gemm_f16_ph_k<<<256, 512, 0, stream>>>(xh, wqkvh, nullptr, qh, 8);

  // KV low-rank transform (K-RoPE fused at load) + global minmax
  mm_init_k<<<1, 64, 0, stream>>>(mmx);
  kv_transform_k<<<dim3(BSROWS / 64, 2), 256, 0, stream>>>(kvb, mk, mv, ct, st, mmx);
  quant_k_codes_k<<<(BSROWS * 128) / 256, 256, 0, stream>>>(kvb, qkc, mmx);
  quant_vt_k<<<dim3(SS / 64, BB), 256, 0, stream>>>(kvb, qvtc, mmx);

  // attention (fused Q-RoPE, fp16 Q) writes fp16 output into xh (x is dead here)
  attn_mfma_k<<<dim3(SS / 64, BB * NHEADS), 256, 0, stream>>>(qh, qkc, qvtc, mmx, ct, st,
                                                              xh);

  // out = attn @ wo^T : fp32 output
  gemm_f16_ph_k<<<256, 512, 0, stream>>>(xh, woh, out, nullptr, 8);
}